// Round 3
// baseline (313.372 us; speedup 1.0000x reference)
//
#include <hip/hip_runtime.h>
#include <hip/hip_bf16.h>

#define B_ROWS 1024
#define OBS_D  512
#define ACT_D  64
#define KD     128
#define CAT_D  192
#define CAP    131072

typedef __attribute__((ext_vector_type(8))) short bf16x8;
typedef __attribute__((ext_vector_type(4))) float f32x4;
typedef __attribute__((ext_vector_type(4))) unsigned short us4;

static __device__ __forceinline__ unsigned short f2bf(float x) {
  unsigned u = __float_as_uint(x);
  return (unsigned short)((u + 0x7fffu + ((u >> 16) & 1u)) >> 16);
}

static __device__ __forceinline__ f32x4 mfma16(bf16x8 a, bf16x8 b, f32x4 c) {
  return __builtin_amdgcn_mfma_f32_16x16x32_bf16(a, b, c, 0, 0, 0);
}

// ---------------------------------------------------------------------------
// Kernel 1: fused MLP. Writes h_scaled = h * (1/tau * log2 e)  and
// hnorm = ||h_scaled|| (softmax shift in the exp2 domain).
// ---------------------------------------------------------------------------
#define MLP_ROWS 8

__global__ __launch_bounds__(256) void mlp_kernel(
    const float* __restrict__ obs, const float* __restrict__ action,
    const float* __restrict__ pred_W, const float* __restrict__ pred_b,
    const float* __restrict__ t1_W, const float* __restrict__ t1_b,
    const float* __restrict__ t2_W, const float* __restrict__ t2_b,
    const float* __restrict__ log_temp,
    float* __restrict__ h_out, float* __restrict__ hnorm) {
  __shared__ float s_obs[MLP_ROWS][OBS_D];
  __shared__ float s_in[MLP_ROWS][KD];
  __shared__ float s_cat[MLP_ROWS][CAT_D];
  __shared__ float s_h1[MLP_ROWS][KD];
  __shared__ float s_ho[MLP_ROWS][KD];
  __shared__ float s_norm[MLP_ROWS];

  const int t = threadIdx.x;
  const int row0 = blockIdx.x * MLP_ROWS;
  const float SCALE = expf(-log_temp[0]) * 1.44269504088896f;

  {
    const float4* g = (const float4*)(obs + (size_t)row0 * OBS_D);
    float4* s = (float4*)&s_obs[0][0];
    for (int i = t; i < MLP_ROWS * OBS_D / 4; i += 256) s[i] = g[i];
  }
  __syncthreads();

  const int k  = t & 127;
  const int r0 = t >> 7;

  {
    float acc[4] = {0.f, 0.f, 0.f, 0.f};
    const float4* w4 = (const float4*)(pred_W + (size_t)k * OBS_D);
    for (int d4 = 0; d4 < OBS_D / 4; ++d4) {
      float4 wv = w4[d4];
      #pragma unroll
      for (int p = 0; p < 4; ++p) {
        const float* sr = &s_obs[r0 + 2 * p][d4 * 4];
        acc[p] += wv.x * sr[0] + wv.y * sr[1] + wv.z * sr[2] + wv.w * sr[3];
      }
    }
    float b = pred_b[k];
    #pragma unroll
    for (int p = 0; p < 4; ++p) s_in[r0 + 2 * p][k] = acc[p] + b;
  }
  __syncthreads();

  {
    int r = t >> 5, l = t & 31;
    float ss = 0.f;
    #pragma unroll
    for (int j = 0; j < 4; ++j) { float v = s_in[r][l + 32 * j]; ss += v * v; }
    #pragma unroll
    for (int off = 16; off; off >>= 1) ss += __shfl_down(ss, off, 32);
    if (l == 0) s_norm[r] = fmaxf(sqrtf(ss), 1e-12f);
  }
  __syncthreads();

  for (int i = t; i < MLP_ROWS * CAT_D; i += 256) {
    int r = i / CAT_D, c = i % CAT_D;
    float v = (c < KD) ? s_in[r][c] / s_norm[r]
                       : action[(size_t)(row0 + r) * ACT_D + (c - KD)];
    s_cat[r][c] = v;
  }
  __syncthreads();

  {
    float acc[4] = {0.f, 0.f, 0.f, 0.f};
    const float4* w4 = (const float4*)(t1_W + (size_t)k * CAT_D);
    for (int d4 = 0; d4 < CAT_D / 4; ++d4) {
      float4 wv = w4[d4];
      #pragma unroll
      for (int p = 0; p < 4; ++p) {
        const float* sr = &s_cat[r0 + 2 * p][d4 * 4];
        acc[p] += wv.x * sr[0] + wv.y * sr[1] + wv.z * sr[2] + wv.w * sr[3];
      }
    }
    float b = t1_b[k];
    #pragma unroll
    for (int p = 0; p < 4; ++p) s_h1[r0 + 2 * p][k] = fmaxf(acc[p] + b, 0.f);
  }
  __syncthreads();

  {
    float acc[4] = {0.f, 0.f, 0.f, 0.f};
    const float4* w4 = (const float4*)(t2_W + (size_t)k * KD);
    for (int d4 = 0; d4 < KD / 4; ++d4) {
      float4 wv = w4[d4];
      #pragma unroll
      for (int p = 0; p < 4; ++p) {
        const float* sr = &s_h1[r0 + 2 * p][d4 * 4];
        acc[p] += wv.x * sr[0] + wv.y * sr[1] + wv.z * sr[2] + wv.w * sr[3];
      }
    }
    float b = t2_b[k];
    #pragma unroll
    for (int p = 0; p < 4; ++p) {
      float hv = (acc[p] + b) * SCALE;
      s_ho[r0 + 2 * p][k] = hv;
      h_out[(size_t)(row0 + r0 + 2 * p) * KD + k] = hv;
    }
  }
  __syncthreads();

  {
    int r = t >> 5, l = t & 31;
    float ss = 0.f;
    #pragma unroll
    for (int j = 0; j < 4; ++j) { float v = s_ho[r][l + 32 * j]; ss += v * v; }
    #pragma unroll
    for (int off = 16; off; off >>= 1) ss += __shfl_down(ss, off, 32);
    if (l == 0) hnorm[row0 + r] = sqrtf(ss);
  }
}

// ---------------------------------------------------------------------------
// Kernel P: keys fp32 -> keys2, fragment-linear image for register-direct
// B loads. Per 128-key chunk (65536 B):
//   [ks:4][plane:2][kw:4][g:2][lk:4][lr:16] x 16B
// holding keys2[key = kw*32+g*16+lr][dims ks*32+lk*8 .. +8] (hi or lo bf16).
// A wave's B-fragment load is then base + lane*16 (fully coalesced 1 KB).
// Thread j handles one (chunk, ks, kw, g, lk, lr) = 8 dims, stores hi+lo.
// ---------------------------------------------------------------------------
__global__ __launch_bounds__(256) void preconv_kernel(
    const float* __restrict__ keys, char* __restrict__ keys2) {
  const int j = blockIdx.x * 256 + threadIdx.x;   // [0, CAP/128 * 2048)
  const int chunk = j >> 11;
  const int s = j & 2047;
  const int ks = s >> 9;
  const int kw = (s >> 7) & 3;
  const int g  = (s >> 6) & 1;
  const int lk = (s >> 4) & 3;
  const int lr = s & 15;
  const int key = chunk * 128 + kw * 32 + g * 16 + lr;
  const int d0  = ks * 32 + lk * 8;

  const float* src = keys + (size_t)key * KD + d0;
  float4 xa = *(const float4*)src;
  float4 xb = *(const float4*)(src + 4);
  float xs[8] = {xa.x, xa.y, xa.z, xa.w, xb.x, xb.y, xb.z, xb.w};
  us4 hi[2], lo[2];
  #pragma unroll
  for (int q = 0; q < 8; ++q) {
    unsigned short hb = f2bf(xs[q]);
    float hf = __uint_as_float((unsigned)hb << 16);
    hi[q >> 2][q & 3] = hb;
    lo[q >> 2][q & 3] = f2bf(xs[q] - hf);
  }
  char* base = keys2 + (size_t)chunk * 65536 + ks * 16384
             + kw * 2048 + g * 1024 + lk * 256 + lr * 16;
  *(us4*)(base)        = hi[0];  *(us4*)(base + 8)        = hi[1];
  *(us4*)(base + 8192) = lo[0];  *(us4*)(base + 8192 + 8) = lo[1];
}

// ---------------------------------------------------------------------------
// Kernel 2 (MFMA, no LDS, no barriers): block = 64 rows x 128 keys per chunk,
// 4 waves each owning a DISJOINT 64row x 32key slice -> B loads go straight
// from the fragment-linear image into VGPRs (zero staging, zero redundancy).
// A (h hi/lo) loop-invariant in registers. C = Ahi*Bh + Alo*Bh + Ahi*Bl.
// Grid 512, XCD-grouped so the 16 row-blocks of a column slice share an L2.
// ---------------------------------------------------------------------------
#define KG2 128

__global__ __launch_bounds__(256, 2) void score_mfma_kernel(
    const float* __restrict__ h, const float* __restrict__ hnorm,
    const char* __restrict__ keys2, const float* __restrict__ values,
    float* __restrict__ accum, int chunks_per_block) {
  const int t = threadIdx.x;
  const int w = t >> 6, l = t & 63;
  const int lr = l & 15, lk = l >> 4;

  // bijective XCD grouping: xcd = blockIdx.x & 7 owns 4 consecutive
  // column slices; the 16 row-blocks of each slice land on the same XCD.
  const int i = blockIdx.x;
  const int idx2 = (i & 7) * 64 + (i >> 3);     // [0,512)
  const int col_slice = idx2 >> 4;              // [0,32)
  const int row_blk   = idx2 & 15;              // [0,16)
  const int row0   = row_blk * 64;
  const int chunk0 = col_slice * chunks_per_block;

  // ---- A fragments: 64 rows, hi/lo bf16 split, resident for all chunks
  bf16x8 Ahi[4][4], Alo[4][4];
  #pragma unroll
  for (int f = 0; f < 4; ++f) {
    const float* hr = h + (size_t)(row0 + f * 16 + lr) * KD + lk * 8;
    #pragma unroll
    for (int ks = 0; ks < 4; ++ks) {
      float4 xa = *(const float4*)(hr + ks * 32);
      float4 xb = *(const float4*)(hr + ks * 32 + 4);
      float xs[8] = {xa.x, xa.y, xa.z, xa.w, xb.x, xb.y, xb.z, xb.w};
      bf16x8 ah, al;
      #pragma unroll
      for (int q = 0; q < 8; ++q) {
        unsigned short hb = f2bf(xs[q]);
        float hf = __uint_as_float((unsigned)hb << 16);
        ah[q] = (short)hb;
        al[q] = (short)f2bf(xs[q] - hf);
      }
      Ahi[f][ks] = ah; Alo[f][ks] = al;
    }
  }

  float m[4][4];
  #pragma unroll
  for (int f = 0; f < 4; ++f)
    #pragma unroll
    for (int r = 0; r < 4; ++r)
      m[f][r] = hnorm[row0 + f * 16 + lk * 4 + r];

  float sacc[4][4], qacc[4][4];
  #pragma unroll
  for (int f = 0; f < 4; ++f)
    #pragma unroll
    for (int r = 0; r < 4; ++r) { sacc[f][r] = 0.f; qacc[f][r] = 0.f; }

  for (int ck = 0; ck < chunks_per_block; ++ck) {
    const char* base = keys2 + (size_t)(chunk0 + ck) * 65536 + w * 2048
                     + (size_t)l * 16;
    #pragma unroll
    for (int g = 0; g < 2; ++g) {
      // B fragments: 8 coalesced 1KB wave-loads, straight to VGPRs
      bf16x8 Bh[4], Bl[4];
      #pragma unroll
      for (int ks = 0; ks < 4; ++ks) {
        Bh[ks] = *(const bf16x8*)(base + ks * 16384 + g * 1024);
        Bl[ks] = *(const bf16x8*)(base + ks * 16384 + 8192 + g * 1024);
      }
      float v = values[(size_t)(chunk0 + ck) * KG2 + w * 32 + g * 16 + lr];

      f32x4 C[4];
      #pragma unroll
      for (int f = 0; f < 4; ++f) C[f] = (f32x4){0.f, 0.f, 0.f, 0.f};
      #pragma unroll
      for (int ks = 0; ks < 4; ++ks) {
        #pragma unroll
        for (int f = 0; f < 4; ++f) C[f] = mfma16(Ahi[f][ks], Bh[ks], C[f]);
        #pragma unroll
        for (int f = 0; f < 4; ++f) C[f] = mfma16(Alo[f][ks], Bh[ks], C[f]);
        #pragma unroll
        for (int f = 0; f < 4; ++f) C[f] = mfma16(Ahi[f][ks], Bl[ks], C[f]);
      }

      #pragma unroll
      for (int f = 0; f < 4; ++f)
        #pragma unroll
        for (int r = 0; r < 4; ++r) {
          float e = exp2f(C[f][r] - m[f][r]);
          sacc[f][r] += e;
          qacc[f][r] = fmaf(e, v, qacc[f][r]);
        }
    }
  }

  #pragma unroll
  for (int f = 0; f < 4; ++f)
    #pragma unroll
    for (int r = 0; r < 4; ++r) {
      float s = sacc[f][r], q = qacc[f][r];
      #pragma unroll
      for (int off = 8; off; off >>= 1) {
        s += __shfl_down(s, off, 16);
        q += __shfl_down(q, off, 16);
      }
      if (lr == 0) {
        int row = row0 + f * 16 + lk * 4 + r;
        atomicAdd(&accum[(size_t)row * 2 + 0], s);
        atomicAdd(&accum[(size_t)row * 2 + 1], q);
      }
    }
}

// ---------------------------------------------------------------------------
// Kernel 2 (fp32 fallback if ws too small): round-1 structure, exp2 domain.
// ---------------------------------------------------------------------------
#define TB 64
#define KG 64
#define SPAD 132

__global__ __launch_bounds__(256) void score_f32_kernel(
    const float* __restrict__ h, const float* __restrict__ hnorm,
    const float* __restrict__ keys, const float* __restrict__ values,
    float* __restrict__ accum, int keys_per_block) {
  __shared__ float s_h[TB][SPAD];
  __shared__ float s_k[KG][SPAD];
  __shared__ float s_v[KG];

  const int t  = threadIdx.x;
  const int kq = t & 15;
  const int rq = t >> 4;
  const int row0 = blockIdx.y * TB;
  const size_t key0 = (size_t)blockIdx.x * (size_t)keys_per_block;

  {
    const float4* g = (const float4*)(h + (size_t)row0 * KD);
    for (int i = t; i < TB * KD / 4; i += 256) {
      int r = i >> 5, d4 = i & 31;
      *(float4*)&s_h[r][d4 * 4] = g[i];
    }
  }

  float m[4];
  #pragma unroll
  for (int i = 0; i < 4; ++i) m[i] = hnorm[row0 + rq * 4 + i];

  float s_acc[4] = {0.f, 0.f, 0.f, 0.f};
  float q_acc[4] = {0.f, 0.f, 0.f, 0.f};

  for (int kg = 0; kg < keys_per_block; kg += KG) {
    __syncthreads();
    {
      const float4* g = (const float4*)(keys + (key0 + kg) * KD);
      for (int i = t; i < KG * KD / 4; i += 256) {
        int ki = i >> 5, d4 = i & 31;
        *(float4*)&s_k[ki][d4 * 4] = g[i];
      }
      if (t < KG) s_v[t] = values[key0 + kg + t];
    }
    __syncthreads();

    float sc[4][4];
    #pragma unroll
    for (int i = 0; i < 4; ++i)
      #pragma unroll
      for (int j = 0; j < 4; ++j) sc[i][j] = 0.f;

    for (int d = 0; d < KD; d += 4) {
      float4 kv[4], hv[4];
      #pragma unroll
      for (int j = 0; j < 4; ++j) kv[j] = *(const float4*)&s_k[kq + 16 * j][d];
      #pragma unroll
      for (int i = 0; i < 4; ++i) hv[i] = *(const float4*)&s_h[rq * 4 + i][d];
      #pragma unroll
      for (int i = 0; i < 4; ++i)
        #pragma unroll
        for (int j = 0; j < 4; ++j)
          sc[i][j] += hv[i].x * kv[j].x + hv[i].y * kv[j].y
                    + hv[i].z * kv[j].z + hv[i].w * kv[j].w;
    }

    #pragma unroll
    for (int j = 0; j < 4; ++j) {
      float v = s_v[kq + 16 * j];
      #pragma unroll
      for (int i = 0; i < 4; ++i) {
        float e = exp2f(sc[i][j] - m[i]);
        s_acc[i] += e;
        q_acc[i] += e * v;
      }
    }
  }

  #pragma unroll
  for (int i = 0; i < 4; ++i) {
    float s = s_acc[i], q = q_acc[i];
    #pragma unroll
    for (int off = 8; off; off >>= 1) {
      s += __shfl_down(s, off, 16);
      q += __shfl_down(q, off, 16);
    }
    if (kq == 0) {
      atomicAdd(&accum[(size_t)(row0 + rq * 4 + i) * 2 + 0], s);
      atomicAdd(&accum[(size_t)(row0 + rq * 4 + i) * 2 + 1], q);
    }
  }
}

// ---------------------------------------------------------------------------
__global__ void finalize_kernel(const float* __restrict__ accum,
                                float* __restrict__ out) {
  int b = blockIdx.x * 256 + threadIdx.x;
  if (b < B_ROWS) out[b] = accum[(size_t)b * 2 + 1] / accum[(size_t)b * 2 + 0];
}

// ---------------------------------------------------------------------------
extern "C" void kernel_launch(void* const* d_in, const int* in_sizes, int n_in,
                              void* d_out, int out_size, void* d_ws, size_t ws_size,
                              hipStream_t stream) {
  const float* obs      = (const float*)d_in[0];
  const float* action   = (const float*)d_in[1];
  const float* pred_W   = (const float*)d_in[2];
  const float* pred_b   = (const float*)d_in[3];
  const float* t1_W     = (const float*)d_in[4];
  const float* t1_b     = (const float*)d_in[5];
  const float* t2_W     = (const float*)d_in[6];
  const float* t2_b     = (const float*)d_in[7];
  const float* keys     = (const float*)d_in[8];
  const float* values   = (const float*)d_in[9];
  const float* log_temp = (const float*)d_in[10];
  float* out = (float*)d_out;

  float* h     = (float*)d_ws;             // 1024*128 f32 = 512 KB
  float* hnorm = h + (size_t)B_ROWS * KD;  // 4 KB
  float* accum = hnorm + B_ROWS;           // 8 KB
  const size_t KEYS2_OFF = 1 << 20;        // 1 MB
  const size_t KEYS2_BYTES = (size_t)CAP * KD * 2 * 2;  // 64 MB
  char* keys2 = (char*)d_ws + KEYS2_OFF;
  const bool big_ws = ws_size >= KEYS2_OFF + KEYS2_BYTES;

  hipMemsetAsync(accum, 0, (size_t)B_ROWS * 2 * sizeof(float), stream);

  hipLaunchKernelGGL(mlp_kernel, dim3(B_ROWS / MLP_ROWS), dim3(256), 0, stream,
                     obs, action, pred_W, pred_b, t1_W, t1_b, t2_W, t2_b,
                     log_temp, h, hnorm);

  if (big_ws) {
    hipLaunchKernelGGL(preconv_kernel, dim3((CAP / KG2) * 2048 / 256), dim3(256),
                       0, stream, keys, keys2);
    const int XB = 32;                      // column slices
    hipLaunchKernelGGL(score_mfma_kernel, dim3(XB * (B_ROWS / 64)), dim3(256),
                       0, stream, h, hnorm, keys2, values, accum,
                       (CAP / KG2) / XB);
  } else {
    const int C_CHUNKS = 32;
    hipLaunchKernelGGL(score_f32_kernel, dim3(C_CHUNKS, B_ROWS / TB), dim3(256),
                       0, stream, h, hnorm, keys, values, accum,
                       CAP / C_CHUNKS);
  }

  hipLaunchKernelGGL(finalize_kernel, dim3(4), dim3(256), 0, stream, accum, out);
}

// Round 4
// 286.710 us; speedup vs baseline: 1.0930x; 1.0930x over previous
//
#include <hip/hip_runtime.h>
#include <hip/hip_bf16.h>

#define B_ROWS 1024
#define OBS_D  512
#define ACT_D  64
#define KD     128
#define CAT_D  192
#define CAP    131072

typedef __attribute__((ext_vector_type(8))) short bf16x8;
typedef __attribute__((ext_vector_type(4))) float f32x4;
typedef __attribute__((ext_vector_type(4))) unsigned short us4;
typedef __attribute__((ext_vector_type(8))) unsigned short us8;

static __device__ __forceinline__ unsigned short f2bf(float x) {
  unsigned u = __float_as_uint(x);
  return (unsigned short)((u + 0x7fffu + ((u >> 16) & 1u)) >> 16);
}

static __device__ __forceinline__ f32x4 mfma16(bf16x8 a, bf16x8 b, f32x4 c) {
  return __builtin_amdgcn_mfma_f32_16x16x32_bf16(a, b, c, 0, 0, 0);
}

// ---------------------------------------------------------------------------
// Kernel 1: fused MLP. Writes h_scaled = h * (1/tau * log2 e)  and
// hnorm = ||h_scaled|| (softmax shift in the exp2 domain).
// ---------------------------------------------------------------------------
#define MLP_ROWS 8

__global__ __launch_bounds__(256) void mlp_kernel(
    const float* __restrict__ obs, const float* __restrict__ action,
    const float* __restrict__ pred_W, const float* __restrict__ pred_b,
    const float* __restrict__ t1_W, const float* __restrict__ t1_b,
    const float* __restrict__ t2_W, const float* __restrict__ t2_b,
    const float* __restrict__ log_temp,
    float* __restrict__ h_out, float* __restrict__ hnorm) {
  __shared__ float s_obs[MLP_ROWS][OBS_D];
  __shared__ float s_in[MLP_ROWS][KD];
  __shared__ float s_cat[MLP_ROWS][CAT_D];
  __shared__ float s_h1[MLP_ROWS][KD];
  __shared__ float s_ho[MLP_ROWS][KD];
  __shared__ float s_norm[MLP_ROWS];

  const int t = threadIdx.x;
  const int row0 = blockIdx.x * MLP_ROWS;
  const float SCALE = expf(-log_temp[0]) * 1.44269504088896f;

  {
    const float4* g = (const float4*)(obs + (size_t)row0 * OBS_D);
    float4* s = (float4*)&s_obs[0][0];
    for (int i = t; i < MLP_ROWS * OBS_D / 4; i += 256) s[i] = g[i];
  }
  __syncthreads();

  const int k  = t & 127;
  const int r0 = t >> 7;

  {
    float acc[4] = {0.f, 0.f, 0.f, 0.f};
    const float4* w4 = (const float4*)(pred_W + (size_t)k * OBS_D);
    for (int d4 = 0; d4 < OBS_D / 4; ++d4) {
      float4 wv = w4[d4];
      #pragma unroll
      for (int p = 0; p < 4; ++p) {
        const float* sr = &s_obs[r0 + 2 * p][d4 * 4];
        acc[p] += wv.x * sr[0] + wv.y * sr[1] + wv.z * sr[2] + wv.w * sr[3];
      }
    }
    float b = pred_b[k];
    #pragma unroll
    for (int p = 0; p < 4; ++p) s_in[r0 + 2 * p][k] = acc[p] + b;
  }
  __syncthreads();

  {
    int r = t >> 5, l = t & 31;
    float ss = 0.f;
    #pragma unroll
    for (int j = 0; j < 4; ++j) { float v = s_in[r][l + 32 * j]; ss += v * v; }
    #pragma unroll
    for (int off = 16; off; off >>= 1) ss += __shfl_down(ss, off, 32);
    if (l == 0) s_norm[r] = fmaxf(sqrtf(ss), 1e-12f);
  }
  __syncthreads();

  for (int i = t; i < MLP_ROWS * CAT_D; i += 256) {
    int r = i / CAT_D, c = i % CAT_D;
    float v = (c < KD) ? s_in[r][c] / s_norm[r]
                       : action[(size_t)(row0 + r) * ACT_D + (c - KD)];
    s_cat[r][c] = v;
  }
  __syncthreads();

  {
    float acc[4] = {0.f, 0.f, 0.f, 0.f};
    const float4* w4 = (const float4*)(t1_W + (size_t)k * CAT_D);
    for (int d4 = 0; d4 < CAT_D / 4; ++d4) {
      float4 wv = w4[d4];
      #pragma unroll
      for (int p = 0; p < 4; ++p) {
        const float* sr = &s_cat[r0 + 2 * p][d4 * 4];
        acc[p] += wv.x * sr[0] + wv.y * sr[1] + wv.z * sr[2] + wv.w * sr[3];
      }
    }
    float b = t1_b[k];
    #pragma unroll
    for (int p = 0; p < 4; ++p) s_h1[r0 + 2 * p][k] = fmaxf(acc[p] + b, 0.f);
  }
  __syncthreads();

  {
    float acc[4] = {0.f, 0.f, 0.f, 0.f};
    const float4* w4 = (const float4*)(t2_W + (size_t)k * KD);
    for (int d4 = 0; d4 < KD / 4; ++d4) {
      float4 wv = w4[d4];
      #pragma unroll
      for (int p = 0; p < 4; ++p) {
        const float* sr = &s_h1[r0 + 2 * p][d4 * 4];
        acc[p] += wv.x * sr[0] + wv.y * sr[1] + wv.z * sr[2] + wv.w * sr[3];
      }
    }
    float b = t2_b[k];
    #pragma unroll
    for (int p = 0; p < 4; ++p) {
      float hv = (acc[p] + b) * SCALE;
      s_ho[r0 + 2 * p][k] = hv;
      h_out[(size_t)(row0 + r0 + 2 * p) * KD + k] = hv;
    }
  }
  __syncthreads();

  {
    int r = t >> 5, l = t & 31;
    float ss = 0.f;
    #pragma unroll
    for (int j = 0; j < 4; ++j) { float v = s_ho[r][l + 32 * j]; ss += v * v; }
    #pragma unroll
    for (int off = 16; off; off >>= 1) ss += __shfl_down(ss, off, 32);
    if (l == 0) hnorm[row0 + r] = sqrtf(ss);
  }
}

// ---------------------------------------------------------------------------
// Kernel P v2: keys fp32 -> fragment-linear image, via LDS transpose.
// Block = 64 keys (half a 128-key chunk). Phase 1: coalesced float4 stage
// into padded LDS [64][132]. Phase 2: every thread emits 16 image-contiguous
// bytes (us8 store) -> reads AND writes fully coalesced.
// Image per 128-key chunk (65536 B), must match score kernel:
//   addr = ks*16384 + plane*8192 + kw*2048 + g*1024 + lk*256 + lr*16
//   content: key = kw*32+g*16+lr, dims [ks*32+lk*8, +8), bf16 hi or lo.
// ---------------------------------------------------------------------------
__global__ __launch_bounds__(256) void preconv_kernel(
    const float* __restrict__ keys, char* __restrict__ keys2) {
  __shared__ float s_f[64][132];   // 33792 B, pad keeps b128 conflicts ~2-way

  const int t = threadIdx.x;
  const int blk = blockIdx.x;          // [0, CAP/64)
  const int chunk = blk >> 1;
  const int half  = blk & 1;           // kw in {2*half, 2*half+1}

  // phase 1: stage 64 keys x 128 dims fp32, coalesced
  {
    const float4* g = (const float4*)(keys + (size_t)blk * 64 * KD);
    #pragma unroll
    for (int it = 0; it < 8; ++it) {
      int idx = t + it * 256;          // float4 index in [0,2048)
      int key = idx >> 5, d4 = idx & 31;
      *(float4*)&s_f[key][d4 * 4] = g[idx];
    }
  }
  __syncthreads();

  // phase 2: emit 2048 x 16B image slots, image-linear across threads
  char* cbase = keys2 + (size_t)chunk * 65536;
  #pragma unroll
  for (int it = 0; it < 8; ++it) {
    int j = t + it * 256;              // [0,2048)
    int lr  = j & 15;
    int lk  = (j >> 4) & 3;
    int g   = (j >> 6) & 1;
    int kwh = (j >> 7) & 1;
    int pl  = (j >> 8) & 1;
    int ks  = (j >> 9) & 3;
    int kw  = half * 2 + kwh;
    int keyloc = kwh * 32 + g * 16 + lr;
    int d0 = ks * 32 + lk * 8;

    float4 xa = *(const float4*)&s_f[keyloc][d0];
    float4 xb = *(const float4*)&s_f[keyloc][d0 + 4];
    float xs[8] = {xa.x, xa.y, xa.z, xa.w, xb.x, xb.y, xb.z, xb.w};
    us8 o;
    #pragma unroll
    for (int q = 0; q < 8; ++q) {
      unsigned short hb = f2bf(xs[q]);
      float hf = __uint_as_float((unsigned)hb << 16);
      unsigned short lb = f2bf(xs[q] - hf);
      o[q] = pl ? lb : hb;
    }
    *(us8*)(cbase + ks * 16384 + pl * 8192 + kw * 2048 + g * 1024
            + lk * 256 + lr * 16) = o;
  }
}

// ---------------------------------------------------------------------------
// Kernel 2 (MFMA, no LDS, no barriers): block = 64 rows x 128 keys per chunk,
// 4 waves each owning a DISJOINT 64row x 32key slice; B fragments register-
// double-buffered (prefetch next g-group while computing current) so L2
// latency hides under the 12-MFMA + exp2 epilogue of the current group.
// A (h hi/lo) loop-invariant. C = Ahi*Bh + Alo*Bh + Ahi*Bl.
// ---------------------------------------------------------------------------
#define KG2 128

__global__ __launch_bounds__(256, 2) void score_mfma_kernel(
    const float* __restrict__ h, const float* __restrict__ hnorm,
    const char* __restrict__ keys2, const float* __restrict__ values,
    float* __restrict__ accum, int chunks_per_block) {
  const int t = threadIdx.x;
  const int w = t >> 6, l = t & 63;
  const int lr = l & 15, lk = l >> 4;

  // bijective XCD grouping: xcd = blockIdx.x & 7 owns 4 consecutive
  // column slices; the 16 row-blocks of each slice land on the same XCD.
  const int i = blockIdx.x;
  const int idx2 = (i & 7) * 64 + (i >> 3);     // [0,512)
  const int col_slice = idx2 >> 4;              // [0,32)
  const int row_blk   = idx2 & 15;              // [0,16)
  const int row0   = row_blk * 64;
  const int chunk0 = col_slice * chunks_per_block;

  // ---- A fragments: 64 rows, hi/lo bf16 split, resident for all chunks
  bf16x8 Ahi[4][4], Alo[4][4];
  #pragma unroll
  for (int f = 0; f < 4; ++f) {
    const float* hr = h + (size_t)(row0 + f * 16 + lr) * KD + lk * 8;
    #pragma unroll
    for (int ks = 0; ks < 4; ++ks) {
      float4 xa = *(const float4*)(hr + ks * 32);
      float4 xb = *(const float4*)(hr + ks * 32 + 4);
      float xs[8] = {xa.x, xa.y, xa.z, xa.w, xb.x, xb.y, xb.z, xb.w};
      bf16x8 ah, al;
      #pragma unroll
      for (int q = 0; q < 8; ++q) {
        unsigned short hb = f2bf(xs[q]);
        float hf = __uint_as_float((unsigned)hb << 16);
        ah[q] = (short)hb;
        al[q] = (short)f2bf(xs[q] - hf);
      }
      Ahi[f][ks] = ah; Alo[f][ks] = al;
    }
  }

  float m[4][4];
  #pragma unroll
  for (int f = 0; f < 4; ++f)
    #pragma unroll
    for (int r = 0; r < 4; ++r)
      m[f][r] = hnorm[row0 + f * 16 + lk * 4 + r];

  float sacc[4][4], qacc[4][4];
  #pragma unroll
  for (int f = 0; f < 4; ++f)
    #pragma unroll
    for (int r = 0; r < 4; ++r) { sacc[f][r] = 0.f; qacc[f][r] = 0.f; }

  const size_t lane_off = (size_t)w * 2048 + (size_t)l * 16;

#define LOADB(BH, BL, VV, CK, G)                                           \
  {                                                                        \
    const char* b_ = keys2 + (size_t)(chunk0 + (CK)) * 65536 + lane_off    \
                   + (G) * 1024;                                           \
    _Pragma("unroll")                                                      \
    for (int ks_ = 0; ks_ < 4; ++ks_) {                                    \
      BH[ks_] = *(const bf16x8*)(b_ + ks_ * 16384);                        \
      BL[ks_] = *(const bf16x8*)(b_ + ks_ * 16384 + 8192);                 \
    }                                                                      \
    VV = values[(size_t)(chunk0 + (CK)) * KG2 + w * 32 + (G) * 16 + lr];   \
  }

#define COMPUTE(BH, BL, VV)                                                \
  {                                                                        \
    f32x4 C[4];                                                            \
    _Pragma("unroll")                                                      \
    for (int f_ = 0; f_ < 4; ++f_) C[f_] = (f32x4){0.f, 0.f, 0.f, 0.f};    \
    _Pragma("unroll")                                                      \
    for (int ks_ = 0; ks_ < 4; ++ks_) {                                    \
      _Pragma("unroll")                                                    \
      for (int f_ = 0; f_ < 4; ++f_)                                       \
        C[f_] = mfma16(Ahi[f_][ks_], BH[ks_], C[f_]);                      \
      _Pragma("unroll")                                                    \
      for (int f_ = 0; f_ < 4; ++f_)                                       \
        C[f_] = mfma16(Alo[f_][ks_], BH[ks_], C[f_]);                      \
      _Pragma("unroll")                                                    \
      for (int f_ = 0; f_ < 4; ++f_)                                       \
        C[f_] = mfma16(Ahi[f_][ks_], BL[ks_], C[f_]);                      \
    }                                                                      \
    _Pragma("unroll")                                                      \
    for (int f_ = 0; f_ < 4; ++f_) {                                       \
      _Pragma("unroll")                                                    \
      for (int r_ = 0; r_ < 4; ++r_) {                                     \
        float e_ = __builtin_amdgcn_exp2f(C[f_][r_] - m[f_][r_]);          \
        sacc[f_][r_] += e_;                                                 \
        qacc[f_][r_] = fmaf(e_, (VV), qacc[f_][r_]);                        \
      }                                                                    \
    }                                                                      \
  }

  bf16x8 Bh0[4], Bl0[4], Bh1[4], Bl1[4];
  float v0, v1;
  LOADB(Bh0, Bl0, v0, 0, 0);

  for (int ck = 0; ck < chunks_per_block; ++ck) {
    LOADB(Bh1, Bl1, v1, ck, 1);          // prefetch g=1
    COMPUTE(Bh0, Bl0, v0);               // compute g=0
    int nk = (ck + 1 < chunks_per_block) ? ck + 1 : ck;
    LOADB(Bh0, Bl0, v0, nk, 0);          // prefetch next chunk g=0
    COMPUTE(Bh1, Bl1, v1);               // compute g=1
  }

#undef LOADB
#undef COMPUTE

  #pragma unroll
  for (int f = 0; f < 4; ++f)
    #pragma unroll
    for (int r = 0; r < 4; ++r) {
      float s = sacc[f][r], q = qacc[f][r];
      #pragma unroll
      for (int off = 8; off; off >>= 1) {
        s += __shfl_down(s, off, 16);
        q += __shfl_down(q, off, 16);
      }
      if (lr == 0) {
        int row = row0 + f * 16 + lk * 4 + r;
        atomicAdd(&accum[(size_t)row * 2 + 0], s);
        atomicAdd(&accum[(size_t)row * 2 + 1], q);
      }
    }
}

// ---------------------------------------------------------------------------
// Kernel 2 (fp32 fallback if ws too small): round-1 structure, exp2 domain.
// ---------------------------------------------------------------------------
#define TB 64
#define KG 64
#define SPAD 132

__global__ __launch_bounds__(256) void score_f32_kernel(
    const float* __restrict__ h, const float* __restrict__ hnorm,
    const float* __restrict__ keys, const float* __restrict__ values,
    float* __restrict__ accum, int keys_per_block) {
  __shared__ float s_h[TB][SPAD];
  __shared__ float s_k[KG][SPAD];
  __shared__ float s_v[KG];

  const int t  = threadIdx.x;
  const int kq = t & 15;
  const int rq = t >> 4;
  const int row0 = blockIdx.y * TB;
  const size_t key0 = (size_t)blockIdx.x * (size_t)keys_per_block;

  {
    const float4* g = (const float4*)(h + (size_t)row0 * KD);
    for (int i = t; i < TB * KD / 4; i += 256) {
      int r = i >> 5, d4 = i & 31;
      *(float4*)&s_h[r][d4 * 4] = g[i];
    }
  }

  float m[4];
  #pragma unroll
  for (int i = 0; i < 4; ++i) m[i] = hnorm[row0 + rq * 4 + i];

  float s_acc[4] = {0.f, 0.f, 0.f, 0.f};
  float q_acc[4] = {0.f, 0.f, 0.f, 0.f};

  for (int kg = 0; kg < keys_per_block; kg += KG) {
    __syncthreads();
    {
      const float4* g = (const float4*)(keys + (key0 + kg) * KD);
      for (int i = t; i < KG * KD / 4; i += 256) {
        int ki = i >> 5, d4 = i & 31;
        *(float4*)&s_k[ki][d4 * 4] = g[i];
      }
      if (t < KG) s_v[t] = values[key0 + kg + t];
    }
    __syncthreads();

    float sc[4][4];
    #pragma unroll
    for (int i = 0; i < 4; ++i)
      #pragma unroll
      for (int j = 0; j < 4; ++j) sc[i][j] = 0.f;

    for (int d = 0; d < KD; d += 4) {
      float4 kv[4], hv[4];
      #pragma unroll
      for (int j = 0; j < 4; ++j) kv[j] = *(const float4*)&s_k[kq + 16 * j][d];
      #pragma unroll
      for (int i = 0; i < 4; ++i) hv[i] = *(const float4*)&s_h[rq * 4 + i][d];
      #pragma unroll
      for (int i = 0; i < 4; ++i)
        #pragma unroll
        for (int j = 0; j < 4; ++j)
          sc[i][j] += hv[i].x * kv[j].x + hv[i].y * kv[j].y
                    + hv[i].z * kv[j].z + hv[i].w * kv[j].w;
    }

    #pragma unroll
    for (int j = 0; j < 4; ++j) {
      float v = s_v[kq + 16 * j];
      #pragma unroll
      for (int i = 0; i < 4; ++i) {
        float e = exp2f(sc[i][j] - m[i]);
        s_acc[i] += e;
        q_acc[i] += e * v;
      }
    }
  }

  #pragma unroll
  for (int i = 0; i < 4; ++i) {
    float s = s_acc[i], q = q_acc[i];
    #pragma unroll
    for (int off = 8; off; off >>= 1) {
      s += __shfl_down(s, off, 16);
      q += __shfl_down(q, off, 16);
    }
    if (kq == 0) {
      atomicAdd(&accum[(size_t)(row0 + rq * 4 + i) * 2 + 0], s);
      atomicAdd(&accum[(size_t)(row0 + rq * 4 + i) * 2 + 1], q);
    }
  }
}

// ---------------------------------------------------------------------------
__global__ void finalize_kernel(const float* __restrict__ accum,
                                float* __restrict__ out) {
  int b = blockIdx.x * 256 + threadIdx.x;
  if (b < B_ROWS) out[b] = accum[(size_t)b * 2 + 1] / accum[(size_t)b * 2 + 0];
}

// ---------------------------------------------------------------------------
extern "C" void kernel_launch(void* const* d_in, const int* in_sizes, int n_in,
                              void* d_out, int out_size, void* d_ws, size_t ws_size,
                              hipStream_t stream) {
  const float* obs      = (const float*)d_in[0];
  const float* action   = (const float*)d_in[1];
  const float* pred_W   = (const float*)d_in[2];
  const float* pred_b   = (const float*)d_in[3];
  const float* t1_W     = (const float*)d_in[4];
  const float* t1_b     = (const float*)d_in[5];
  const float* t2_W     = (const float*)d_in[6];
  const float* t2_b     = (const float*)d_in[7];
  const float* keys     = (const float*)d_in[8];
  const float* values   = (const float*)d_in[9];
  const float* log_temp = (const float*)d_in[10];
  float* out = (float*)d_out;

  float* h     = (float*)d_ws;             // 1024*128 f32 = 512 KB
  float* hnorm = h + (size_t)B_ROWS * KD;  // 4 KB
  float* accum = hnorm + B_ROWS;           // 8 KB
  const size_t KEYS2_OFF = 1 << 20;        // 1 MB
  const size_t KEYS2_BYTES = (size_t)CAP * KD * 2 * 2;  // 64 MB
  char* keys2 = (char*)d_ws + KEYS2_OFF;
  const bool big_ws = ws_size >= KEYS2_OFF + KEYS2_BYTES;

  hipMemsetAsync(accum, 0, (size_t)B_ROWS * 2 * sizeof(float), stream);

  hipLaunchKernelGGL(mlp_kernel, dim3(B_ROWS / MLP_ROWS), dim3(256), 0, stream,
                     obs, action, pred_W, pred_b, t1_W, t1_b, t2_W, t2_b,
                     log_temp, h, hnorm);

  if (big_ws) {
    hipLaunchKernelGGL(preconv_kernel, dim3(CAP / 64), dim3(256), 0, stream,
                       keys, keys2);
    const int XB = 32;                      // column slices
    hipLaunchKernelGGL(score_mfma_kernel, dim3(XB * (B_ROWS / 64)), dim3(256),
                       0, stream, h, hnorm, keys2, values, accum,
                       (CAP / KG2) / XB);
  } else {
    const int C_CHUNKS = 32;
    hipLaunchKernelGGL(score_f32_kernel, dim3(C_CHUNKS, B_ROWS / TB), dim3(256),
                       0, stream, h, hnorm, keys, values, accum,
                       CAP / C_CHUNKS);
  }

  hipLaunchKernelGGL(finalize_kernel, dim3(4), dim3(256), 0, stream, accum, out);
}